// Round 4
// baseline (380.278 us; speedup 1.0000x reference)
//
#include <hip/hip_runtime.h>
#include <hip/hip_fp16.h>
#include <cstdint>
#include <cstddef>

#define NN 50000
#define NE 800000

typedef _Float16 half8 __attribute__((ext_vector_type(8)));
typedef float    f32x4 __attribute__((ext_vector_type(4)));

static __device__ __forceinline__ float lrelu02(float x){ return x > 0.f ? x : 0.2f*x; }

static __device__ __forceinline__ float2 h2f(uint32_t u){
  __half2 h = *reinterpret_cast<__half2*>(&u);
  return __half22float2(h);
}
static __device__ __forceinline__ uint32_t f2h(float a, float b){
  __half2 h = __floats2half2_rn(a, b);
  return *reinterpret_cast<uint32_t*>(&h);
}
// accumulate 8 halves (one uint4) into acc[0..8)
static __device__ __forceinline__ void acc8p(float* acc, uint4 raw, float p){
  float2 f0=h2f(raw.x), f1=h2f(raw.y), f2=h2f(raw.z), f3=h2f(raw.w);
  acc[0]+=p*f0.x; acc[1]+=p*f0.y; acc[2]+=p*f1.x; acc[3]+=p*f1.y;
  acc[4]+=p*f2.x; acc[5]+=p*f2.y; acc[6]+=p*f3.x; acc[7]+=p*f3.y;
}
static __device__ __forceinline__ void acc8s(float* acc, uint4 raw){
  float2 f0=h2f(raw.x), f1=h2f(raw.y), f2=h2f(raw.z), f3=h2f(raw.w);
  acc[0]+=f0.x; acc[1]+=f0.y; acc[2]+=f1.x; acc[3]+=f1.y;
  acc[4]+=f2.x; acc[5]+=f2.y; acc[6]+=f3.x; acc[7]+=f3.y;
}

// ---------------- CSR preprocessing: single-pass, direct L2 atomics ------------------
__global__ __launch_bounds__(256) void count_kernel(const int* __restrict__ dst,
                                                    int* __restrict__ cnt, int E){
  const int stride = gridDim.x * 256;
  for (int e = blockIdx.x*256 + threadIdx.x; e < E; e += stride)
    atomicAdd(&cnt[dst[e]], 1);
}

__global__ __launch_bounds__(1024) void scan1_kernel(const int* __restrict__ cnt,
      int* __restrict__ incl, int* __restrict__ bsum, int N){
  __shared__ int tmp[1024];
  const int t = threadIdx.x;
  const int i = blockIdx.x*1024 + t;
  int v = (i < N) ? cnt[i] : 0;
  tmp[t] = v;
  __syncthreads();
  #pragma unroll
  for (int off = 1; off < 1024; off <<= 1){
    int u = (t >= off) ? tmp[t-off] : 0;
    __syncthreads();
    tmp[t] += u;
    __syncthreads();
  }
  if (i < N) incl[i] = tmp[t];
  if (t == 1023) bsum[blockIdx.x] = tmp[t];
}

__global__ void scan2_kernel(int* __restrict__ bsum, int NB){
  const int t = threadIdx.x;
  int own = (t < NB) ? bsum[t] : 0;
  int v = own;
  #pragma unroll
  for (int off = 1; off < 64; off <<= 1){
    int u = __shfl_up(v, off, 64);
    if (t >= off) v += u;
  }
  if (t < NB) bsum[t] = v - own;
}

__global__ void scan3_kernel(const int* __restrict__ cnt, const int* __restrict__ incl,
      const int* __restrict__ bsum, int* __restrict__ rp, int* __restrict__ fillp,
      float* __restrict__ dinv, int N){
  const int i = blockIdx.x*blockDim.x + threadIdx.x;
  if (i >= N) return;
  const int c = cnt[i];
  const int e = bsum[i >> 10] + incl[i] - c;
  rp[i] = e; fillp[i] = e;
  dinv[i] = rsqrtf((float)(c + 1));
  if (i == N-1) rp[N] = e + c;
}

__global__ __launch_bounds__(256) void fill_kernel(const int* __restrict__ src,
      const int* __restrict__ dst, int* __restrict__ fillp,
      int* __restrict__ col, int E){
  const int stride = gridDim.x * 256;
  for (int e = blockIdx.x*256 + threadIdx.x; e < E; e += stride){
    const int d = dst[e];
    const int s = src[e];
    const int pos = atomicAdd(&fillp[d], 1);
    col[pos] = s;
  }
}

// ---------------- MFMA f16 GEMM: C[M x 64*NT] = A[MxK] @ B[K x 64*NT] ----------------
// Full output width per block (NT 64-col tiles) -> A read exactly once from HBM.
// B staged to LDS once (transposed fp16), single barrier, barrier-free unrolled K-loop,
// A fragments read directly from global (coalesced 16-row x 128B segments).
// AHALF: A is fp16. DOTS: al/ar = C@a_src/a_dst, complete per row -> direct store.
// Fragments: A[m=lane&15][k=quad*8+j]; B[k][n=lane&15]; C/D: col=lane&15, row=quad*4+reg.
template<int K, int NT, bool AHALF, bool HALF_OUT, bool DOTS>
__global__ __launch_bounds__(256) void gemm_mfma_kernel(
    const void* __restrict__ Av, const float* __restrict__ B,
    const float* __restrict__ bias, const float* __restrict__ rowscale,
    const float* __restrict__ avs, const float* __restrict__ avd,
    float* __restrict__ al, float* __restrict__ ar,
    void* __restrict__ Cv, int M, int N)
{
  constexpr int LDK = K + 8;
  __shared__ __align__(16) _Float16 Bt[64*NT][LDK];   // Bt[n][k]
  const int bm = blockIdx.x * 64;
  const int t  = threadIdx.x;
  const int w    = t >> 6;
  const int lane = t & 63;
  const int m    = lane & 15;
  const int quad = lane >> 4;

  // stage B transposed: float4 reads along n (coalesced), scalar LDS writes
  #pragma unroll
  for (int i = t; i < K*16*NT; i += 256){
    const int k  = i / (16*NT);
    const int n4 = (i % (16*NT)) << 2;
    const float4 v = *(const float4*)(B + (size_t)k*N + n4);
    Bt[n4+0][k] = (_Float16)v.x;
    Bt[n4+1][k] = (_Float16)v.y;
    Bt[n4+2][k] = (_Float16)v.z;
    Bt[n4+3][k] = (_Float16)v.w;
  }

  f32x4 acc[4*NT];
  #pragma unroll
  for (int ct = 0; ct < 4*NT; ++ct) acc[ct] = (f32x4){0.f,0.f,0.f,0.f};

  const int row = bm + w*16 + m;
  __syncthreads();

  #pragma unroll
  for (int k0 = 0; k0 < K; k0 += 32){
    union { half8 h; uint4 u; uint32_t w[4]; } ua;
    if constexpr (AHALF){
      if (row < M){
        ua.u = *(const uint4*)((const _Float16*)Av + (size_t)row*K + k0 + quad*8);
      } else {
        ua.u = make_uint4(0u,0u,0u,0u);
      }
    } else {
      if (row < M){
        const float* Arow = (const float*)Av + (size_t)row*K;
        const float4 va = *(const float4*)(Arow + k0 + quad*8);
        const float4 vb = *(const float4*)(Arow + k0 + quad*8 + 4);
        ua.w[0] = f2h(va.x, va.y);
        ua.w[1] = f2h(va.z, va.w);
        ua.w[2] = f2h(vb.x, vb.y);
        ua.w[3] = f2h(vb.z, vb.w);
      } else {
        ua.u = make_uint4(0u,0u,0u,0u);
      }
    }
    const half8 af = ua.h;
    #pragma unroll
    for (int ct = 0; ct < 4*NT; ++ct){
      const half8 bf = *(const half8*)&Bt[ct*16 + m][k0 + quad*8];
      acc[ct] = __builtin_amdgcn_mfma_f32_16x16x32_f16(af, bf, acc[ct], 0, 0, 0);
    }
  }

  // epilogue: C[row=bm+16w+4*quad+reg][col=16ct+m]
  float rs[4];
  #pragma unroll
  for (int reg = 0; reg < 4; ++reg){
    const int r = bm + w*16 + quad*4 + reg;
    rs[reg] = (rowscale && r < M) ? rowscale[r] : 1.f;
  }
  float dal[4] = {0.f,0.f,0.f,0.f};
  float dar[4] = {0.f,0.f,0.f,0.f};
  #pragma unroll
  for (int ct = 0; ct < 4*NT; ++ct){
    const int colg = ct*16 + m;
    const float bv = bias ? bias[colg] : 0.f;
    float s_c = 0.f, d_c = 0.f;
    if constexpr (DOTS){ s_c = avs[colg]; d_c = avd[colg]; }
    #pragma unroll
    for (int reg = 0; reg < 4; ++reg){
      const int r = bm + w*16 + quad*4 + reg;
      if (r < M){
        const float v = rs[reg]*acc[ct][reg] + bv;
        if constexpr (DOTS){ dal[reg] += v*s_c; dar[reg] += v*d_c; }
        if constexpr (HALF_OUT){
          ((__half*)Cv)[(size_t)r*N + colg] = __float2half(v);
        } else {
          ((float*)Cv)[(size_t)r*N + colg] = v;
        }
      }
    }
  }
  if constexpr (DOTS){
    #pragma unroll
    for (int off = 1; off < 16; off <<= 1){
      #pragma unroll
      for (int reg = 0; reg < 4; ++reg){
        dal[reg] += __shfl_xor(dal[reg], off, 64);
        dar[reg] += __shfl_xor(dar[reg], off, 64);
      }
    }
    if (m == 0){
      #pragma unroll
      for (int reg = 0; reg < 4; ++reg){
        const int r = bm + w*16 + quad*4 + reg;
        if (r < M){
          al[r] = dal[reg];                // block covers full N -> complete sums
          ar[r] = dar[reg];
        }
      }
    }
  }
}

// ---------------- GCN aggregation F=128: ONE 16-LANE GROUP PER NODE ------------------
__global__ __launch_bounds__(256) void gcn_agg128_kernel(
    const __half* __restrict__ H, const int* __restrict__ rp, const int* __restrict__ col,
    const float* __restrict__ dinv, const float* __restrict__ bias,
    __half* __restrict__ out, int N)
{
  const int t  = threadIdx.x;
  const int n  = blockIdx.x * 16 + (t >> 4);
  const int gl = t & 15;
  if (n >= N) return;
  const float dn = dinv[n];
  float acc[8];
  {
    uint4 raw = *(const uint4*)(H + (size_t)n*128 + gl*8);
    float2 f0=h2f(raw.x), f1=h2f(raw.y), f2=h2f(raw.z), f3=h2f(raw.w);
    acc[0]=f0.x; acc[1]=f0.y; acc[2]=f1.x; acc[3]=f1.y;
    acc[4]=f2.x; acc[5]=f2.y; acc[6]=f3.x; acc[7]=f3.y;
  }
  const int s0 = rp[n], s1 = rp[n+1];
  for (int c0 = s0; c0 < s1; c0 += 16){
    const int nc = min(16, s1 - c0);
    int sl = (gl < nc) ? col[c0 + gl] : 0;
    #pragma unroll 2
    for (int j = 0; j < nc; ++j){
      const int s = __shfl(sl, j, 16);
      acc8s(acc, *(const uint4*)(H + (size_t)s*128 + gl*8));
    }
  }
  const float* bp = bias + gl*8;
  float4 b0 = *(const float4*)(bp);
  float4 b1 = *(const float4*)(bp + 4);
  uint4 o;
  o.x = f2h(dn*acc[0] + b0.x, dn*acc[1] + b0.y);
  o.y = f2h(dn*acc[2] + b0.z, dn*acc[3] + b0.w);
  o.z = f2h(dn*acc[4] + b1.x, dn*acc[5] + b1.y);
  o.w = f2h(dn*acc[6] + b1.z, dn*acc[7] + b1.w);
  *(uint4*)(out + (size_t)n*128 + gl*8) = o;
}

// ---------------- GCN aggregation F=64: ONE 8-LANE GROUP PER NODE --------------------
__global__ __launch_bounds__(256) void gcn_agg64_kernel(
    const __half* __restrict__ H, const int* __restrict__ rp, const int* __restrict__ col,
    const float* __restrict__ dinv, const float* __restrict__ bias,
    __half* __restrict__ out, int N)
{
  const int t  = threadIdx.x;
  const int n  = blockIdx.x * 32 + (t >> 3);
  const int gl = t & 7;
  if (n >= N) return;
  const float dn = dinv[n];
  float acc[8];
  {
    uint4 raw = *(const uint4*)(H + (size_t)n*64 + gl*8);
    float2 f0=h2f(raw.x), f1=h2f(raw.y), f2=h2f(raw.z), f3=h2f(raw.w);
    acc[0]=f0.x; acc[1]=f0.y; acc[2]=f1.x; acc[3]=f1.y;
    acc[4]=f2.x; acc[5]=f2.y; acc[6]=f3.x; acc[7]=f3.y;
  }
  const int s0 = rp[n], s1 = rp[n+1];
  for (int c0 = s0; c0 < s1; c0 += 8){
    const int nc = min(8, s1 - c0);
    int sl = (gl < nc) ? col[c0 + gl] : 0;
    #pragma unroll 2
    for (int j = 0; j < nc; ++j){
      const int s = __shfl(sl, j, 8);
      acc8s(acc, *(const uint4*)(H + (size_t)s*64 + gl*8));
    }
  }
  const float* bp = bias + gl*8;
  float4 b0 = *(const float4*)(bp);
  float4 b1 = *(const float4*)(bp + 4);
  uint4 o;
  o.x = f2h(dn*acc[0] + b0.x, dn*acc[1] + b0.y);
  o.y = f2h(dn*acc[2] + b0.z, dn*acc[3] + b0.w);
  o.z = f2h(dn*acc[4] + b1.x, dn*acc[5] + b1.y);
  o.w = f2h(dn*acc[6] + b1.z, dn*acc[7] + b1.w);
  *(uint4*)(out + (size_t)n*64 + gl*8) = o;
}

// ---------------- GAT aggregation: ONE 16-LANE GROUP PER NODE ------------------------
__global__ __launch_bounds__(256) void gat_agg_kernel(
    const __half* __restrict__ HG, const int* __restrict__ rp, const int* __restrict__ col,
    const float* __restrict__ al, const float* __restrict__ ar,
    const float* __restrict__ bias, __half* __restrict__ out, int N)
{
  const int t  = threadIdx.x;
  const int n  = blockIdx.x * 16 + (t >> 4);
  const int gl = t & 15;
  if (n >= N) return;
  const float arn = ar[n];
  const float pself = __expf(lrelu02(al[n] + arn));
  float lpart = 0.f;
  float acc[8];
  {
    uint4 raw = *(const uint4*)(HG + (size_t)n*128 + gl*8);
    float2 f0=h2f(raw.x), f1=h2f(raw.y), f2=h2f(raw.z), f3=h2f(raw.w);
    acc[0]=pself*f0.x; acc[1]=pself*f0.y; acc[2]=pself*f1.x; acc[3]=pself*f1.y;
    acc[4]=pself*f2.x; acc[5]=pself*f2.y; acc[6]=pself*f3.x; acc[7]=pself*f3.y;
  }
  const int s0 = rp[n], s1 = rp[n+1];
  for (int c0 = s0; c0 < s1; c0 += 16){
    const int nc = min(16, s1 - c0);
    int   sl = (gl < nc) ? col[c0 + gl] : 0;
    float pl = (gl < nc) ? __expf(lrelu02(al[sl] + arn)) : 0.f;
    lpart += pl;
    #pragma unroll 2
    for (int j = 0; j < nc; ++j){
      const int   s = __shfl(sl, j, 16);
      const float p = __shfl(pl, j, 16);
      acc8p(acc, *(const uint4*)(HG + (size_t)s*128 + gl*8), p);
    }
  }
  #pragma unroll
  for (int off = 8; off > 0; off >>= 1) lpart += __shfl_xor(lpart, off, 16);
  const float inv = 1.f / (pself + lpart);
  const float* bp = bias + gl*8;
  float4 b0 = *(const float4*)(bp);
  float4 b1 = *(const float4*)(bp + 4);
  uint4 o;
  o.x = f2h(fmaxf(acc[0]*inv + b0.x, 0.f), fmaxf(acc[1]*inv + b0.y, 0.f));
  o.y = f2h(fmaxf(acc[2]*inv + b0.z, 0.f), fmaxf(acc[3]*inv + b0.w, 0.f));
  o.z = f2h(fmaxf(acc[4]*inv + b1.x, 0.f), fmaxf(acc[5]*inv + b1.y, 0.f));
  o.w = f2h(fmaxf(acc[6]*inv + b1.z, 0.f), fmaxf(acc[7]*inv + b1.w, 0.f));
  *(uint4*)(out + (size_t)n*128 + gl*8) = o;
}

// ---------------- launch ----------------
extern "C" void kernel_launch(void* const* d_in, const int* in_sizes, int n_in,
                              void* d_out, int out_size, void* d_ws, size_t ws_size,
                              hipStream_t stream)
{
  const float* x     = (const float*)d_in[0];
  const int*   ei    = (const int*)d_in[1];
  const float* W1    = (const float*)d_in[2];
  const float* b1    = (const float*)d_in[3];
  const float* Wg    = (const float*)d_in[4];
  const float* a_src = (const float*)d_in[5];
  const float* a_dst = (const float*)d_in[6];
  const float* bg    = (const float*)d_in[7];
  const float* W2    = (const float*)d_in[8];
  const float* b2    = (const float*)d_in[9];
  const float* Wf    = (const float*)d_in[10];
  const float* bf    = (const float*)d_in[11];
  const int N = NN, E = NE;
  const int* src = ei;
  const int* dst = ei + E;

  char* p = (char*)d_ws;
  auto alloc = [&](size_t bytes)->char*{
    char* r = p; p += (bytes + 511) & ~size_t(511); return r;
  };
  int*    cnt   = (int*)   alloc((size_t)N*4);
  int*    incl  = (int*)   alloc((size_t)N*4);
  int*    bsum  = (int*)   alloc(64*4);
  int*    rp    = (int*)   alloc((size_t)(N+1)*4);
  int*    fillp = (int*)   alloc((size_t)N*4);
  int*    col   = (int*)   alloc((size_t)E*4);
  float*  dinv  = (float*) alloc((size_t)N*4);
  float*  alar_ = (float*) alloc((size_t)N*8);     // al | ar contiguous
  __half* H16   = (__half*)alloc((size_t)N*128*2);
  __half* Hb    = (__half*)alloc((size_t)N*128*2);
  float*  al    = alar_;
  float*  ar    = alar_ + N;

  const int NB = (N + 1023) / 1024;

  hipMemsetAsync(cnt, 0, (size_t)N*4, stream);
  count_kernel<<<2048, 256, 0, stream>>>(dst, cnt, E);
  scan1_kernel<<<NB, 1024, 0, stream>>>(cnt, incl, bsum, N);
  scan2_kernel<<<1, 64, 0, stream>>>(bsum, NB);
  scan3_kernel<<<(N+255)/256, 256, 0, stream>>>(cnt, incl, bsum, rp, fillp, dinv, N);
  fill_kernel<<<2048, 256, 0, stream>>>(src, dst, fillp, col, E);

  const int gm  = (N + 63) / 64;
  const int g16 = (N + 15) / 16;
  const int g32 = (N + 31) / 32;

  // GEMM1: H16 = fp16( dinv ⊙ (x @ W1) )  [K=192, NT=2 -> N=128], fp32 A (read once)
  gemm_mfma_kernel<192,2,false,true,false><<<gm, 256, 0, stream>>>(
      x, W1, nullptr, dinv, nullptr, nullptr, nullptr, nullptr, H16, N, 128);
  // AGG1 (GCN): H16 -> Hb (+b1), fp16
  gcn_agg128_kernel<<<g16, 256, 0, stream>>>(H16, rp, col, dinv, b1, Hb, N);
  // GEMM2: H16 = fp16( Hb @ Wg ) (HG), fp16 A, fused al/ar (direct store)
  gemm_mfma_kernel<128,2,true,true,true><<<gm, 256, 0, stream>>>(
      Hb, Wg, nullptr, nullptr, a_src, a_dst, al, ar, H16, N, 128);
  // GAT: H16 -> Hb (+bg, relu fused), fp16
  gat_agg_kernel<<<g16, 256, 0, stream>>>(H16, rp, col, al, ar, bg, Hb, N);
  // GEMM3: H16 = fp16( dinv ⊙ (Hb @ W2) )  [K=128, NT=1 -> N=64], fp16 A
  gemm_mfma_kernel<128,1,true,true,false><<<gm, 256, 0, stream>>>(
      Hb, W2, nullptr, dinv, nullptr, nullptr, nullptr, nullptr, H16, N, 64);
  // AGG2 (GCN): H16 -> Hb (+b2), fp16, F=64
  gcn_agg64_kernel<<<g32, 256, 0, stream>>>(H16, rp, col, dinv, b2, Hb, N);
  // GEMM4: out = Hb @ Wf + bf (fp32 out)  [K=64, NT=3 -> N=192], fp16 A (read once)
  gemm_mfma_kernel<64,3,true,false,false><<<gm, 256, 0, stream>>>(
      Hb, Wf, bf, nullptr, nullptr, nullptr, nullptr, nullptr, d_out, N, 192);
}

// Round 5
// 340.655 us; speedup vs baseline: 1.1163x; 1.1163x over previous
//
#include <hip/hip_runtime.h>
#include <hip/hip_fp16.h>
#include <cstdint>
#include <cstddef>

#define NN 50000
#define NE 800000
#define RNG 8
#define RSZ ((NN + RNG - 1) / RNG)
#define CPR 128

typedef _Float16 half8 __attribute__((ext_vector_type(8)));
typedef float    f32x4 __attribute__((ext_vector_type(4)));

static __device__ __forceinline__ float lrelu02(float x){ return x > 0.f ? x : 0.2f*x; }

static __device__ __forceinline__ float2 h2f(uint32_t u){
  __half2 h = *reinterpret_cast<__half2*>(&u);
  return __half22float2(h);
}
static __device__ __forceinline__ uint32_t f2h(float a, float b){
  __half2 h = __floats2half2_rn(a, b);
  return *reinterpret_cast<uint32_t*>(&h);
}
// accumulate 8 halves (one uint4) into acc[0..8)
static __device__ __forceinline__ void acc8p(float* acc, uint4 raw, float p){
  float2 f0=h2f(raw.x), f1=h2f(raw.y), f2=h2f(raw.z), f3=h2f(raw.w);
  acc[0]+=p*f0.x; acc[1]+=p*f0.y; acc[2]+=p*f1.x; acc[3]+=p*f1.y;
  acc[4]+=p*f2.x; acc[5]+=p*f2.y; acc[6]+=p*f3.x; acc[7]+=p*f3.y;
}
static __device__ __forceinline__ void acc8s(float* acc, uint4 raw){
  float2 f0=h2f(raw.x), f1=h2f(raw.y), f2=h2f(raw.z), f3=h2f(raw.w);
  acc[0]+=f0.x; acc[1]+=f0.y; acc[2]+=f1.x; acc[3]+=f1.y;
  acc[4]+=f2.x; acc[5]+=f2.y; acc[6]+=f3.x; acc[7]+=f3.y;
}

// ---------------- CSR preprocessing ----------------
// count: range-partitioned (XCD-local atomics, proven in r3) + rank capture.
// rank[e] = position of edge e within its dst's segment -> fill needs NO atomics.
__global__ __launch_bounds__(256) void count_kernel(const int* __restrict__ dst,
      int* __restrict__ cnt, int* __restrict__ rank, int E){
  const int r  = blockIdx.x % RNG;
  const int i  = blockIdx.x / RNG;
  const int lo = r * RSZ;
  const int hi = min(lo + RSZ, NN);
  const int cs = (E + CPR - 1) / CPR;
  const int e1 = min((i+1)*cs, E);
  for (int e = i*cs + threadIdx.x; e < e1; e += 256){
    const int d = dst[e];
    if (d >= lo && d < hi) rank[e] = atomicAdd(&cnt[d], 1);
  }
}

__global__ __launch_bounds__(1024) void scan1_kernel(const int* __restrict__ cnt,
      int* __restrict__ incl, int* __restrict__ bsum, int N){
  __shared__ int tmp[1024];
  const int t = threadIdx.x;
  const int i = blockIdx.x*1024 + t;
  int v = (i < N) ? cnt[i] : 0;
  tmp[t] = v;
  __syncthreads();
  #pragma unroll
  for (int off = 1; off < 1024; off <<= 1){
    int u = (t >= off) ? tmp[t-off] : 0;
    __syncthreads();
    tmp[t] += u;
    __syncthreads();
  }
  if (i < N) incl[i] = tmp[t];
  if (t == 1023) bsum[blockIdx.x] = tmp[t];
}

__global__ void scan2_kernel(int* __restrict__ bsum, int NB){
  const int t = threadIdx.x;
  int own = (t < NB) ? bsum[t] : 0;
  int v = own;
  #pragma unroll
  for (int off = 1; off < 64; off <<= 1){
    int u = __shfl_up(v, off, 64);
    if (t >= off) v += u;
  }
  if (t < NB) bsum[t] = v - own;
}

__global__ void scan3_kernel(const int* __restrict__ cnt, const int* __restrict__ incl,
      const int* __restrict__ bsum, int* __restrict__ rp,
      float* __restrict__ dinv, int N){
  const int i = blockIdx.x*blockDim.x + threadIdx.x;
  if (i >= N) return;
  const int c = cnt[i];
  const int e = bsum[i >> 10] + incl[i] - c;
  rp[i] = e;
  dinv[i] = rsqrtf((float)(c + 1));
  if (i == N-1) rp[N] = e + c;
}

// atomic-free scatter: col[rp[dst]+rank] = src. Fire-and-forget stores only.
__global__ __launch_bounds__(256) void scatter_kernel(const int* __restrict__ src,
      const int* __restrict__ dst, const int* __restrict__ rank,
      const int* __restrict__ rp, int* __restrict__ col, int E){
  const int stride = gridDim.x * 256;
  for (int e = blockIdx.x*256 + threadIdx.x; e < E; e += stride){
    col[rp[dst[e]] + rank[e]] = src[e];
  }
}

// ---------------- MFMA f16 GEMM: C[M x 64*NT] = A[MxK] @ B[K x 64*NT] ----------------
// Full output width per block (NT 64-col tiles) -> A read exactly once from HBM.
// B staged to LDS once (transposed fp16), single barrier, barrier-free unrolled K-loop,
// A fragments read directly from global (coalesced 16-row x 128B segments).
// AHALF: A is fp16. DOTS: al/ar = C@a_src/a_dst, complete per row -> direct store.
template<int K, int NT, bool AHALF, bool HALF_OUT, bool DOTS>
__global__ __launch_bounds__(256) void gemm_mfma_kernel(
    const void* __restrict__ Av, const float* __restrict__ B,
    const float* __restrict__ bias, const float* __restrict__ rowscale,
    const float* __restrict__ avs, const float* __restrict__ avd,
    float* __restrict__ al, float* __restrict__ ar,
    void* __restrict__ Cv, int M, int N)
{
  constexpr int LDK = K + 8;
  __shared__ __align__(16) _Float16 Bt[64*NT][LDK];   // Bt[n][k]
  const int bm = blockIdx.x * 64;
  const int t  = threadIdx.x;
  const int w    = t >> 6;
  const int lane = t & 63;
  const int m    = lane & 15;
  const int quad = lane >> 4;

  #pragma unroll
  for (int i = t; i < K*16*NT; i += 256){
    const int k  = i / (16*NT);
    const int n4 = (i % (16*NT)) << 2;
    const float4 v = *(const float4*)(B + (size_t)k*N + n4);
    Bt[n4+0][k] = (_Float16)v.x;
    Bt[n4+1][k] = (_Float16)v.y;
    Bt[n4+2][k] = (_Float16)v.z;
    Bt[n4+3][k] = (_Float16)v.w;
  }

  f32x4 acc[4*NT];
  #pragma unroll
  for (int ct = 0; ct < 4*NT; ++ct) acc[ct] = (f32x4){0.f,0.f,0.f,0.f};

  const int row = bm + w*16 + m;
  __syncthreads();

  #pragma unroll
  for (int k0 = 0; k0 < K; k0 += 32){
    union { half8 h; uint4 u; uint32_t w[4]; } ua;
    if constexpr (AHALF){
      if (row < M){
        ua.u = *(const uint4*)((const _Float16*)Av + (size_t)row*K + k0 + quad*8);
      } else {
        ua.u = make_uint4(0u,0u,0u,0u);
      }
    } else {
      if (row < M){
        const float* Arow = (const float*)Av + (size_t)row*K;
        const float4 va = *(const float4*)(Arow + k0 + quad*8);
        const float4 vb = *(const float4*)(Arow + k0 + quad*8 + 4);
        ua.w[0] = f2h(va.x, va.y);
        ua.w[1] = f2h(va.z, va.w);
        ua.w[2] = f2h(vb.x, vb.y);
        ua.w[3] = f2h(vb.z, vb.w);
      } else {
        ua.u = make_uint4(0u,0u,0u,0u);
      }
    }
    const half8 af = ua.h;
    #pragma unroll
    for (int ct = 0; ct < 4*NT; ++ct){
      const half8 bf = *(const half8*)&Bt[ct*16 + m][k0 + quad*8];
      acc[ct] = __builtin_amdgcn_mfma_f32_16x16x32_f16(af, bf, acc[ct], 0, 0, 0);
    }
  }

  // epilogue: C[row=bm+16w+4*quad+reg][col=16ct+m]
  float rs[4];
  #pragma unroll
  for (int reg = 0; reg < 4; ++reg){
    const int r = bm + w*16 + quad*4 + reg;
    rs[reg] = (rowscale && r < M) ? rowscale[r] : 1.f;
  }
  float dal[4] = {0.f,0.f,0.f,0.f};
  float dar[4] = {0.f,0.f,0.f,0.f};
  #pragma unroll
  for (int ct = 0; ct < 4*NT; ++ct){
    const int colg = ct*16 + m;
    const float bv = bias ? bias[colg] : 0.f;
    float s_c = 0.f, d_c = 0.f;
    if constexpr (DOTS){ s_c = avs[colg]; d_c = avd[colg]; }
    #pragma unroll
    for (int reg = 0; reg < 4; ++reg){
      const int r = bm + w*16 + quad*4 + reg;
      if (r < M){
        const float v = rs[reg]*acc[ct][reg] + bv;
        if constexpr (DOTS){ dal[reg] += v*s_c; dar[reg] += v*d_c; }
        if constexpr (HALF_OUT){
          ((__half*)Cv)[(size_t)r*N + colg] = __float2half(v);
        } else {
          ((float*)Cv)[(size_t)r*N + colg] = v;
        }
      }
    }
  }
  if constexpr (DOTS){
    #pragma unroll
    for (int off = 1; off < 16; off <<= 1){
      #pragma unroll
      for (int reg = 0; reg < 4; ++reg){
        dal[reg] += __shfl_xor(dal[reg], off, 64);
        dar[reg] += __shfl_xor(dar[reg], off, 64);
      }
    }
    if (m == 0){
      #pragma unroll
      for (int reg = 0; reg < 4; ++reg){
        const int r = bm + w*16 + quad*4 + reg;
        if (r < M){
          al[r] = dal[reg];                // block covers full N -> complete sums
          ar[r] = dar[reg];
        }
      }
    }
  }
}

// ---------------- GCN aggregation F=128: ONE 16-LANE GROUP PER NODE ------------------
__global__ __launch_bounds__(256) void gcn_agg128_kernel(
    const __half* __restrict__ H, const int* __restrict__ rp, const int* __restrict__ col,
    const float* __restrict__ dinv, const float* __restrict__ bias,
    __half* __restrict__ out, int N)
{
  const int t  = threadIdx.x;
  const int n  = blockIdx.x * 16 + (t >> 4);
  const int gl = t & 15;
  if (n >= N) return;
  const float dn = dinv[n];
  float acc[8];
  {
    uint4 raw = *(const uint4*)(H + (size_t)n*128 + gl*8);
    float2 f0=h2f(raw.x), f1=h2f(raw.y), f2=h2f(raw.z), f3=h2f(raw.w);
    acc[0]=f0.x; acc[1]=f0.y; acc[2]=f1.x; acc[3]=f1.y;
    acc[4]=f2.x; acc[5]=f2.y; acc[6]=f3.x; acc[7]=f3.y;
  }
  const int s0 = rp[n], s1 = rp[n+1];
  for (int c0 = s0; c0 < s1; c0 += 16){
    const int nc = min(16, s1 - c0);
    int sl = (gl < nc) ? col[c0 + gl] : 0;
    #pragma unroll 2
    for (int j = 0; j < nc; ++j){
      const int s = __shfl(sl, j, 16);
      acc8s(acc, *(const uint4*)(H + (size_t)s*128 + gl*8));
    }
  }
  const float* bp = bias + gl*8;
  float4 b0 = *(const float4*)(bp);
  float4 b1 = *(const float4*)(bp + 4);
  uint4 o;
  o.x = f2h(dn*acc[0] + b0.x, dn*acc[1] + b0.y);
  o.y = f2h(dn*acc[2] + b0.z, dn*acc[3] + b0.w);
  o.z = f2h(dn*acc[4] + b1.x, dn*acc[5] + b1.y);
  o.w = f2h(dn*acc[6] + b1.z, dn*acc[7] + b1.w);
  *(uint4*)(out + (size_t)n*128 + gl*8) = o;
}

// ---------------- GCN aggregation F=64: ONE 8-LANE GROUP PER NODE --------------------
__global__ __launch_bounds__(256) void gcn_agg64_kernel(
    const __half* __restrict__ H, const int* __restrict__ rp, const int* __restrict__ col,
    const float* __restrict__ dinv, const float* __restrict__ bias,
    __half* __restrict__ out, int N)
{
  const int t  = threadIdx.x;
  const int n  = blockIdx.x * 32 + (t >> 3);
  const int gl = t & 7;
  if (n >= N) return;
  const float dn = dinv[n];
  float acc[8];
  {
    uint4 raw = *(const uint4*)(H + (size_t)n*64 + gl*8);
    float2 f0=h2f(raw.x), f1=h2f(raw.y), f2=h2f(raw.z), f3=h2f(raw.w);
    acc[0]=f0.x; acc[1]=f0.y; acc[2]=f1.x; acc[3]=f1.y;
    acc[4]=f2.x; acc[5]=f2.y; acc[6]=f3.x; acc[7]=f3.y;
  }
  const int s0 = rp[n], s1 = rp[n+1];
  for (int c0 = s0; c0 < s1; c0 += 8){
    const int nc = min(8, s1 - c0);
    int sl = (gl < nc) ? col[c0 + gl] : 0;
    #pragma unroll 2
    for (int j = 0; j < nc; ++j){
      const int s = __shfl(sl, j, 8);
      acc8s(acc, *(const uint4*)(H + (size_t)s*64 + gl*8));
    }
  }
  const float* bp = bias + gl*8;
  float4 b0 = *(const float4*)(bp);
  float4 b1 = *(const float4*)(bp + 4);
  uint4 o;
  o.x = f2h(dn*acc[0] + b0.x, dn*acc[1] + b0.y);
  o.y = f2h(dn*acc[2] + b0.z, dn*acc[3] + b0.w);
  o.z = f2h(dn*acc[4] + b1.x, dn*acc[5] + b1.y);
  o.w = f2h(dn*acc[6] + b1.z, dn*acc[7] + b1.w);
  *(uint4*)(out + (size_t)n*64 + gl*8) = o;
}

// ---------------- GAT aggregation: ONE 16-LANE GROUP PER NODE ------------------------
__global__ __launch_bounds__(256) void gat_agg_kernel(
    const __half* __restrict__ HG, const int* __restrict__ rp, const int* __restrict__ col,
    const float* __restrict__ al, const float* __restrict__ ar,
    const float* __restrict__ bias, __half* __restrict__ out, int N)
{
  const int t  = threadIdx.x;
  const int n  = blockIdx.x * 16 + (t >> 4);
  const int gl = t & 15;
  if (n >= N) return;
  const float arn = ar[n];
  const float pself = __expf(lrelu02(al[n] + arn));
  float lpart = 0.f;
  float acc[8];
  {
    uint4 raw = *(const uint4*)(HG + (size_t)n*128 + gl*8);
    float2 f0=h2f(raw.x), f1=h2f(raw.y), f2=h2f(raw.z), f3=h2f(raw.w);
    acc[0]=pself*f0.x; acc[1]=pself*f0.y; acc[2]=pself*f1.x; acc[3]=pself*f1.y;
    acc[4]=pself*f2.x; acc[5]=pself*f2.y; acc[6]=pself*f3.x; acc[7]=pself*f3.y;
  }
  const int s0 = rp[n], s1 = rp[n+1];
  for (int c0 = s0; c0 < s1; c0 += 16){
    const int nc = min(16, s1 - c0);
    int   sl = (gl < nc) ? col[c0 + gl] : 0;
    float pl = (gl < nc) ? __expf(lrelu02(al[sl] + arn)) : 0.f;
    lpart += pl;
    #pragma unroll 2
    for (int j = 0; j < nc; ++j){
      const int   s = __shfl(sl, j, 16);
      const float p = __shfl(pl, j, 16);
      acc8p(acc, *(const uint4*)(HG + (size_t)s*128 + gl*8), p);
    }
  }
  #pragma unroll
  for (int off = 8; off > 0; off >>= 1) lpart += __shfl_xor(lpart, off, 16);
  const float inv = 1.f / (pself + lpart);
  const float* bp = bias + gl*8;
  float4 b0 = *(const float4*)(bp);
  float4 b1 = *(const float4*)(bp + 4);
  uint4 o;
  o.x = f2h(fmaxf(acc[0]*inv + b0.x, 0.f), fmaxf(acc[1]*inv + b0.y, 0.f));
  o.y = f2h(fmaxf(acc[2]*inv + b0.z, 0.f), fmaxf(acc[3]*inv + b0.w, 0.f));
  o.z = f2h(fmaxf(acc[4]*inv + b1.x, 0.f), fmaxf(acc[5]*inv + b1.y, 0.f));
  o.w = f2h(fmaxf(acc[6]*inv + b1.z, 0.f), fmaxf(acc[7]*inv + b1.w, 0.f));
  *(uint4*)(out + (size_t)n*128 + gl*8) = o;
}

// ---------------- launch ----------------
extern "C" void kernel_launch(void* const* d_in, const int* in_sizes, int n_in,
                              void* d_out, int out_size, void* d_ws, size_t ws_size,
                              hipStream_t stream)
{
  const float* x     = (const float*)d_in[0];
  const int*   ei    = (const int*)d_in[1];
  const float* W1    = (const float*)d_in[2];
  const float* b1    = (const float*)d_in[3];
  const float* Wg    = (const float*)d_in[4];
  const float* a_src = (const float*)d_in[5];
  const float* a_dst = (const float*)d_in[6];
  const float* bg    = (const float*)d_in[7];
  const float* W2    = (const float*)d_in[8];
  const float* b2    = (const float*)d_in[9];
  const float* Wf    = (const float*)d_in[10];
  const float* bf    = (const float*)d_in[11];
  const int N = NN, E = NE;
  const int* src = ei;
  const int* dst = ei + E;

  char* p = (char*)d_ws;
  auto alloc = [&](size_t bytes)->char*{
    char* r = p; p += (bytes + 511) & ~size_t(511); return r;
  };
  int*    cnt   = (int*)   alloc((size_t)N*4);
  int*    incl  = (int*)   alloc((size_t)N*4);
  int*    bsum  = (int*)   alloc(64*4);
  int*    rp    = (int*)   alloc((size_t)(N+1)*4);
  int*    rank  = (int*)   alloc((size_t)E*4);
  int*    col   = (int*)   alloc((size_t)E*4);
  float*  dinv  = (float*) alloc((size_t)N*4);
  float*  alar_ = (float*) alloc((size_t)N*8);     // al | ar contiguous
  __half* H16   = (__half*)alloc((size_t)N*128*2);
  __half* Hb    = (__half*)alloc((size_t)N*128*2);
  float*  al    = alar_;
  float*  ar    = alar_ + N;

  const int NB = (N + 1023) / 1024;

  hipMemsetAsync(cnt, 0, (size_t)N*4, stream);
  count_kernel<<<RNG*CPR, 256, 0, stream>>>(dst, cnt, rank, E);
  scan1_kernel<<<NB, 1024, 0, stream>>>(cnt, incl, bsum, N);
  scan2_kernel<<<1, 64, 0, stream>>>(bsum, NB);
  scan3_kernel<<<(N+255)/256, 256, 0, stream>>>(cnt, incl, bsum, rp, dinv, N);
  scatter_kernel<<<2048, 256, 0, stream>>>(src, dst, rank, rp, col, E);

  const int gm  = (N + 63) / 64;
  const int g16 = (N + 15) / 16;
  const int g32 = (N + 31) / 32;

  // GEMM1: H16 = fp16( dinv ⊙ (x @ W1) )  [K=192, NT=2 -> N=128], fp32 A (read once)
  gemm_mfma_kernel<192,2,false,true,false><<<gm, 256, 0, stream>>>(
      x, W1, nullptr, dinv, nullptr, nullptr, nullptr, nullptr, H16, N, 128);
  // AGG1 (GCN): H16 -> Hb (+b1), fp16
  gcn_agg128_kernel<<<g16, 256, 0, stream>>>(H16, rp, col, dinv, b1, Hb, N);
  // GEMM2: H16 = fp16( Hb @ Wg ) (HG), fp16 A, fused al/ar (direct store)
  gemm_mfma_kernel<128,2,true,true,true><<<gm, 256, 0, stream>>>(
      Hb, Wg, nullptr, nullptr, a_src, a_dst, al, ar, H16, N, 128);
  // GAT: H16 -> Hb (+bg, relu fused), fp16
  gat_agg_kernel<<<g16, 256, 0, stream>>>(H16, rp, col, al, ar, bg, Hb, N);
  // GEMM3: H16 = fp16( dinv ⊙ (Hb @ W2) )  [K=128, NT=1 -> N=64], fp16 A
  gemm_mfma_kernel<128,1,true,true,false><<<gm, 256, 0, stream>>>(
      Hb, W2, nullptr, dinv, nullptr, nullptr, nullptr, nullptr, H16, N, 64);
  // AGG2 (GCN): H16 -> Hb (+b2), fp16, F=64
  gcn_agg64_kernel<<<g32, 256, 0, stream>>>(H16, rp, col, dinv, b2, Hb, N);
  // GEMM4: out = Hb @ Wf + bf (fp32 out)  [K=64, NT=3 -> N=192], fp16 A (read once)
  gemm_mfma_kernel<64,3,true,false,false><<<gm, 256, 0, stream>>>(
      Hb, Wf, bf, nullptr, nullptr, nullptr, nullptr, nullptr, d_out, N, 192);
}

// Round 6
// 330.829 us; speedup vs baseline: 1.1495x; 1.0297x over previous
//
#include <hip/hip_runtime.h>
#include <hip/hip_fp16.h>
#include <cstdint>
#include <cstddef>

#define NN 50000
#define NE 800000
#define RNG 8
#define RSZ ((NN + RNG - 1) / RNG)
#define CPR 256

typedef _Float16 half8 __attribute__((ext_vector_type(8)));
typedef float    f32x4 __attribute__((ext_vector_type(4)));

static __device__ __forceinline__ float lrelu02(float x){ return x > 0.f ? x : 0.2f*x; }

static __device__ __forceinline__ float2 h2f(uint32_t u){
  __half2 h = *reinterpret_cast<__half2*>(&u);
  return __half22float2(h);
}
static __device__ __forceinline__ uint32_t f2h(float a, float b){
  __half2 h = __floats2half2_rn(a, b);
  return *reinterpret_cast<uint32_t*>(&h);
}
// accumulate 8 halves (one uint4) into acc[0..8)
static __device__ __forceinline__ void acc8p(float* acc, uint4 raw, float p){
  float2 f0=h2f(raw.x), f1=h2f(raw.y), f2=h2f(raw.z), f3=h2f(raw.w);
  acc[0]+=p*f0.x; acc[1]+=p*f0.y; acc[2]+=p*f1.x; acc[3]+=p*f1.y;
  acc[4]+=p*f2.x; acc[5]+=p*f2.y; acc[6]+=p*f3.x; acc[7]+=p*f3.y;
}
static __device__ __forceinline__ void acc8s(float* acc, uint4 raw){
  float2 f0=h2f(raw.x), f1=h2f(raw.y), f2=h2f(raw.z), f3=h2f(raw.w);
  acc[0]+=f0.x; acc[1]+=f0.y; acc[2]+=f1.x; acc[3]+=f1.y;
  acc[4]+=f2.x; acc[5]+=f2.y; acc[6]+=f3.x; acc[7]+=f3.y;
}

// ---------------- weight pre-swizzle: B fp32 [K][N] -> MFMA-fragment-order fp16 -------
// Bsw[((k0/32)*(N/16) + ct)*512 + lane*8 + j] = B[k0 + (lane>>4)*8 + j][ct*16 + (lane&15)]
// -> GEMM B-fragment = one coalesced uint4 per lane, no LDS needed.
__global__ __launch_bounds__(256) void pack_all_kernel(
    const float* __restrict__ W1, const float* __restrict__ Wg,
    const float* __restrict__ W2, const float* __restrict__ Wf,
    _Float16* __restrict__ B1, _Float16* __restrict__ B2,
    _Float16* __restrict__ B3, _Float16* __restrict__ B4)
{
  const int b = blockIdx.x;
  const float* B; _Float16* O; int K, N, base;
  if      (b < 96)  { B = W1; O = B1; K = 192; N = 128; base = 0;   }  // 24576
  else if (b < 160) { B = Wg; O = B2; K = 128; N = 128; base = 96;  }  // 16384
  else if (b < 192) { B = W2; O = B3; K = 128; N = 64;  base = 160; }  // 8192
  else              { B = Wf; O = B4; K = 64;  N = 192; base = 192; }  // 12288
  const int i = (b - base)*256 + threadIdx.x;
  if (i >= K*N) return;
  const int j    = i & 7;
  const int lane = (i >> 3) & 63;
  const int tile = i >> 9;
  const int ntl  = N >> 4;
  const int ct   = tile % ntl;
  const int k0   = (tile / ntl) << 5;
  const int k = k0 + ((lane >> 4) << 3) + j;
  const int n = (ct << 4) + (lane & 15);
  O[i] = (_Float16)B[(size_t)k*N + n];
}

// ---------------- CSR preprocessing: range-partitioned (XCD-local atomics) -----------
__global__ __launch_bounds__(256) void count_kernel(const int* __restrict__ dst,
                                                    int* __restrict__ cnt, int E){
  const int r  = blockIdx.x % RNG;
  const int i  = blockIdx.x / RNG;
  const int lo = r * RSZ;
  const int hi = min(lo + RSZ, NN);
  const int cs = (E + CPR - 1) / CPR;
  const int e1 = min((i+1)*cs, E);
  for (int e = i*cs + threadIdx.x; e < e1; e += 256){
    const int d = dst[e];
    if (d >= lo && d < hi) atomicAdd(&cnt[d], 1);
  }
}

__global__ __launch_bounds__(1024) void scan1_kernel(const int* __restrict__ cnt,
      int* __restrict__ incl, int* __restrict__ bsum, int N){
  __shared__ int tmp[1024];
  const int t = threadIdx.x;
  const int i = blockIdx.x*1024 + t;
  int v = (i < N) ? cnt[i] : 0;
  tmp[t] = v;
  __syncthreads();
  #pragma unroll
  for (int off = 1; off < 1024; off <<= 1){
    int u = (t >= off) ? tmp[t-off] : 0;
    __syncthreads();
    tmp[t] += u;
    __syncthreads();
  }
  if (i < N) incl[i] = tmp[t];
  if (t == 1023) bsum[blockIdx.x] = tmp[t];
}

__global__ void scan2_kernel(int* __restrict__ bsum, int NB){
  const int t = threadIdx.x;
  int own = (t < NB) ? bsum[t] : 0;
  int v = own;
  #pragma unroll
  for (int off = 1; off < 64; off <<= 1){
    int u = __shfl_up(v, off, 64);
    if (t >= off) v += u;
  }
  if (t < NB) bsum[t] = v - own;
}

__global__ void scan3_kernel(const int* __restrict__ cnt, const int* __restrict__ incl,
      const int* __restrict__ bsum, int* __restrict__ rp, int* __restrict__ fillp,
      float* __restrict__ dinv, int N){
  const int i = blockIdx.x*blockDim.x + threadIdx.x;
  if (i >= N) return;
  const int c = cnt[i];
  const int e = bsum[i >> 10] + incl[i] - c;
  rp[i] = e; fillp[i] = e;
  dinv[i] = rsqrtf((float)(c + 1));
  if (i == N-1) rp[N] = e + c;
}

__global__ __launch_bounds__(256) void fill_kernel(const int* __restrict__ src,
      const int* __restrict__ dst, int* __restrict__ fillp,
      int* __restrict__ col, int E){
  const int r  = blockIdx.x % RNG;
  const int i  = blockIdx.x / RNG;
  const int lo = r * RSZ;
  const int hi = min(lo + RSZ, NN);
  const int cs = (E + CPR - 1) / CPR;
  const int e1 = min((i+1)*cs, E);
  for (int e = i*cs + threadIdx.x; e < e1; e += 256){
    const int d = dst[e];
    if (d >= lo && d < hi){
      const int s = src[e];
      const int pos = atomicAdd(&fillp[d], 1);
      col[pos] = s;
    }
  }
}

// ---------------- MFMA f16 GEMM, LDS-FREE: C[M x 64*NT] = A[MxK] @ Bsw ---------------
// B pre-swizzled into fragment order (pack_all_kernel): per (k0,ct) each lane loads its
// 8-half B-fragment as one coalesced uint4 from global (L2-resident, shared by all
// blocks). No LDS, no barrier, no bank conflicts; fully unrolled K-loop.
// A fragments read directly from global (coalesced 16-row x 128B segments).
// AHALF: A is fp16. DOTS: al/ar = C@a_src/a_dst, complete per row -> direct store.
// Fragments: A[m=lane&15][k=quad*8+j]; C/D: col=lane&15, row=quad*4+reg.
template<int K, int NT, bool AHALF, bool HALF_OUT, bool DOTS>
__global__ __launch_bounds__(256) void gemm_mfma_kernel(
    const void* __restrict__ Av, const _Float16* __restrict__ Bsw,
    const float* __restrict__ bias, const float* __restrict__ rowscale,
    const float* __restrict__ avs, const float* __restrict__ avd,
    float* __restrict__ al, float* __restrict__ ar,
    void* __restrict__ Cv, int M, int N)
{
  constexpr int NTL = NT*4;             // 16-col tiles
  const int bm = blockIdx.x * 64;
  const int t  = threadIdx.x;
  const int w    = t >> 6;
  const int lane = t & 63;
  const int m    = lane & 15;
  const int quad = lane >> 4;

  f32x4 acc[NTL];
  #pragma unroll
  for (int ct = 0; ct < NTL; ++ct) acc[ct] = (f32x4){0.f,0.f,0.f,0.f};

  const int row = bm + w*16 + m;
  const _Float16* bp = Bsw + lane*8;

  #pragma unroll
  for (int k0 = 0; k0 < K; k0 += 32){
    union { half8 h; uint4 u; uint32_t w[4]; } ua;
    if constexpr (AHALF){
      if (row < M){
        ua.u = *(const uint4*)((const _Float16*)Av + (size_t)row*K + k0 + quad*8);
      } else {
        ua.u = make_uint4(0u,0u,0u,0u);
      }
    } else {
      if (row < M){
        const float* Arow = (const float*)Av + (size_t)row*K;
        const float4 va = *(const float4*)(Arow + k0 + quad*8);
        const float4 vb = *(const float4*)(Arow + k0 + quad*8 + 4);
        ua.w[0] = f2h(va.x, va.y);
        ua.w[1] = f2h(va.z, va.w);
        ua.w[2] = f2h(vb.x, vb.y);
        ua.w[3] = f2h(vb.z, vb.w);
      } else {
        ua.u = make_uint4(0u,0u,0u,0u);
      }
    }
    const half8 af = ua.h;
    #pragma unroll
    for (int ct = 0; ct < NTL; ++ct){
      const half8 bf = *(const half8*)(bp + ((size_t)((k0>>5)*NTL + ct))*512);
      acc[ct] = __builtin_amdgcn_mfma_f32_16x16x32_f16(af, bf, acc[ct], 0, 0, 0);
    }
  }

  // epilogue: C[row=bm+16w+4*quad+reg][col=16ct+m]
  float rs[4];
  #pragma unroll
  for (int reg = 0; reg < 4; ++reg){
    const int r = bm + w*16 + quad*4 + reg;
    rs[reg] = (rowscale && r < M) ? rowscale[r] : 1.f;
  }
  float dal[4] = {0.f,0.f,0.f,0.f};
  float dar[4] = {0.f,0.f,0.f,0.f};
  #pragma unroll
  for (int ct = 0; ct < NTL; ++ct){
    const int colg = ct*16 + m;
    const float bv = bias ? bias[colg] : 0.f;
    float s_c = 0.f, d_c = 0.f;
    if constexpr (DOTS){ s_c = avs[colg]; d_c = avd[colg]; }
    #pragma unroll
    for (int reg = 0; reg < 4; ++reg){
      const int r = bm + w*16 + quad*4 + reg;
      if (r < M){
        const float v = rs[reg]*acc[ct][reg] + bv;
        if constexpr (DOTS){ dal[reg] += v*s_c; dar[reg] += v*d_c; }
        if constexpr (HALF_OUT){
          ((__half*)Cv)[(size_t)r*N + colg] = __float2half(v);
        } else {
          ((float*)Cv)[(size_t)r*N + colg] = v;
        }
      }
    }
  }
  if constexpr (DOTS){
    #pragma unroll
    for (int off = 1; off < 16; off <<= 1){
      #pragma unroll
      for (int reg = 0; reg < 4; ++reg){
        dal[reg] += __shfl_xor(dal[reg], off, 64);
        dar[reg] += __shfl_xor(dar[reg], off, 64);
      }
    }
    if (m == 0){
      #pragma unroll
      for (int reg = 0; reg < 4; ++reg){
        const int r = bm + w*16 + quad*4 + reg;
        if (r < M){
          al[r] = dal[reg];                // block covers full N -> complete sums
          ar[r] = dar[reg];
        }
      }
    }
  }
}

// ---------------- GCN aggregation F=128: ONE 16-LANE GROUP PER NODE ------------------
__global__ __launch_bounds__(256) void gcn_agg128_kernel(
    const __half* __restrict__ H, const int* __restrict__ rp, const int* __restrict__ col,
    const float* __restrict__ dinv, const float* __restrict__ bias,
    __half* __restrict__ out, int N)
{
  const int t  = threadIdx.x;
  const int n  = blockIdx.x * 16 + (t >> 4);
  const int gl = t & 15;
  if (n >= N) return;
  const float dn = dinv[n];
  float acc[8];
  {
    uint4 raw = *(const uint4*)(H + (size_t)n*128 + gl*8);
    float2 f0=h2f(raw.x), f1=h2f(raw.y), f2=h2f(raw.z), f3=h2f(raw.w);
    acc[0]=f0.x; acc[1]=f0.y; acc[2]=f1.x; acc[3]=f1.y;
    acc[4]=f2.x; acc[5]=f2.y; acc[6]=f3.x; acc[7]=f3.y;
  }
  const int s0 = rp[n], s1 = rp[n+1];
  for (int c0 = s0; c0 < s1; c0 += 16){
    const int nc = min(16, s1 - c0);
    int sl = (gl < nc) ? col[c0 + gl] : 0;
    #pragma unroll 2
    for (int j = 0; j < nc; ++j){
      const int s = __shfl(sl, j, 16);
      acc8s(acc, *(const uint4*)(H + (size_t)s*128 + gl*8));
    }
  }
  const float* bp = bias + gl*8;
  float4 b0 = *(const float4*)(bp);
  float4 b1 = *(const float4*)(bp + 4);
  uint4 o;
  o.x = f2h(dn*acc[0] + b0.x, dn*acc[1] + b0.y);
  o.y = f2h(dn*acc[2] + b0.z, dn*acc[3] + b0.w);
  o.z = f2h(dn*acc[4] + b1.x, dn*acc[5] + b1.y);
  o.w = f2h(dn*acc[6] + b1.z, dn*acc[7] + b1.w);
  *(uint4*)(out + (size_t)n*128 + gl*8) = o;
}

// ---------------- GCN aggregation F=64: ONE 8-LANE GROUP PER NODE --------------------
__global__ __launch_bounds__(256) void gcn_agg64_kernel(
    const __half* __restrict__ H, const int* __restrict__ rp, const int* __restrict__ col,
    const float* __restrict__ dinv, const float* __restrict__ bias,
    __half* __restrict__ out, int N)
{
  const int t  = threadIdx.x;
  const int n  = blockIdx.x * 32 + (t >> 3);
  const int gl = t & 7;
  if (n >= N) return;
  const float dn = dinv[n];
  float acc[8];
  {
    uint4 raw = *(const uint4*)(H + (size_t)n*64 + gl*8);
    float2 f0=h2f(raw.x), f1=h2f(raw.y), f2=h2f(raw.z), f3=h2f(raw.w);
    acc[0]=f0.x; acc[1]=f0.y; acc[2]=f1.x; acc[3]=f1.y;
    acc[4]=f2.x; acc[5]=f2.y; acc[6]=f3.x; acc[7]=f3.y;
  }
  const int s0 = rp[n], s1 = rp[n+1];
  for (int c0 = s0; c0 < s1; c0 += 8){
    const int nc = min(8, s1 - c0);
    int sl = (gl < nc) ? col[c0 + gl] : 0;
    #pragma unroll 2
    for (int j = 0; j < nc; ++j){
      const int s = __shfl(sl, j, 8);
      acc8s(acc, *(const uint4*)(H + (size_t)s*64 + gl*8));
    }
  }
  const float* bp = bias + gl*8;
  float4 b0 = *(const float4*)(bp);
  float4 b1 = *(const float4*)(bp + 4);
  uint4 o;
  o.x = f2h(dn*acc[0] + b0.x, dn*acc[1] + b0.y);
  o.y = f2h(dn*acc[2] + b0.z, dn*acc[3] + b0.w);
  o.z = f2h(dn*acc[4] + b1.x, dn*acc[5] + b1.y);
  o.w = f2h(dn*acc[6] + b1.z, dn*acc[7] + b1.w);
  *(uint4*)(out + (size_t)n*64 + gl*8) = o;
}

// ---------------- GAT aggregation: ONE 16-LANE GROUP PER NODE ------------------------
__global__ __launch_bounds__(256) void gat_agg_kernel(
    const __half* __restrict__ HG, const int* __restrict__ rp, const int* __restrict__ col,
    const float* __restrict__ al, const float* __restrict__ ar,
    const float* __restrict__ bias, __half* __restrict__ out, int N)
{
  const int t  = threadIdx.x;
  const int n  = blockIdx.x * 16 + (t >> 4);
  const int gl = t & 15;
  if (n >= N) return;
  const float arn = ar[n];
  const float pself = __expf(lrelu02(al[n] + arn));
  float lpart = 0.f;
  float acc[8];
  {
    uint4 raw = *(const uint4*)(HG + (size_t)n*128 + gl*8);
    float2 f0=h2f(raw.x), f1=h2f(raw.y), f2=h2f(raw.z), f3=h2f(raw.w);
    acc[0]=pself*f0.x; acc[1]=pself*f0.y; acc[2]=pself*f1.x; acc[3]=pself*f1.y;
    acc[4]=pself*f2.x; acc[5]=pself*f2.y; acc[6]=pself*f3.x; acc[7]=pself*f3.y;
  }
  const int s0 = rp[n], s1 = rp[n+1];
  for (int c0 = s0; c0 < s1; c0 += 16){
    const int nc = min(16, s1 - c0);
    int   sl = (gl < nc) ? col[c0 + gl] : 0;
    float pl = (gl < nc) ? __expf(lrelu02(al[sl] + arn)) : 0.f;
    lpart += pl;
    #pragma unroll 2
    for (int j = 0; j < nc; ++j){
      const int   s = __shfl(sl, j, 16);
      const float p = __shfl(pl, j, 16);
      acc8p(acc, *(const uint4*)(HG + (size_t)s*128 + gl*8), p);
    }
  }
  #pragma unroll
  for (int off = 8; off > 0; off >>= 1) lpart += __shfl_xor(lpart, off, 16);
  const float inv = 1.f / (pself + lpart);
  const float* bp = bias + gl*8;
  float4 b0 = *(const float4*)(bp);
  float4 b1 = *(const float4*)(bp + 4);
  uint4 o;
  o.x = f2h(fmaxf(acc[0]*inv + b0.x, 0.f), fmaxf(acc[1]*inv + b0.y, 0.f));
  o.y = f2h(fmaxf(acc[2]*inv + b0.z, 0.f), fmaxf(acc[3]*inv + b0.w, 0.f));
  o.z = f2h(fmaxf(acc[4]*inv + b1.x, 0.f), fmaxf(acc[5]*inv + b1.y, 0.f));
  o.w = f2h(fmaxf(acc[6]*inv + b1.z, 0.f), fmaxf(acc[7]*inv + b1.w, 0.f));
  *(uint4*)(out + (size_t)n*128 + gl*8) = o;
}

// ---------------- launch ----------------
extern "C" void kernel_launch(void* const* d_in, const int* in_sizes, int n_in,
                              void* d_out, int out_size, void* d_ws, size_t ws_size,
                              hipStream_t stream)
{
  const float* x     = (const float*)d_in[0];
  const int*   ei    = (const int*)d_in[1];
  const float* W1    = (const float*)d_in[2];
  const float* b1    = (const float*)d_in[3];
  const float* Wg    = (const float*)d_in[4];
  const float* a_src = (const float*)d_in[5];
  const float* a_dst = (const float*)d_in[6];
  const float* bg    = (const float*)d_in[7];
  const float* W2    = (const float*)d_in[8];
  const float* b2    = (const float*)d_in[9];
  const float* Wf    = (const float*)d_in[10];
  const float* bf    = (const float*)d_in[11];
  const int N = NN, E = NE;
  const int* src = ei;
  const int* dst = ei + E;

  char* p = (char*)d_ws;
  auto alloc = [&](size_t bytes)->char*{
    char* r = p; p += (bytes + 511) & ~size_t(511); return r;
  };
  int*      cnt   = (int*)     alloc((size_t)N*4);
  int*      incl  = (int*)     alloc((size_t)N*4);
  int*      bsum  = (int*)     alloc(64*4);
  int*      rp    = (int*)     alloc((size_t)(N+1)*4);
  int*      fillp = (int*)     alloc((size_t)N*4);
  int*      col   = (int*)     alloc((size_t)E*4);
  float*    dinv  = (float*)   alloc((size_t)N*4);
  float*    alar_ = (float*)   alloc((size_t)N*8);     // al | ar contiguous
  __half*   H16   = (__half*)  alloc((size_t)N*128*2);
  __half*   Hb    = (__half*)  alloc((size_t)N*128*2);
  _Float16* B1    = (_Float16*)alloc(24576*2);
  _Float16* B2    = (_Float16*)alloc(16384*2);
  _Float16* B3    = (_Float16*)alloc(8192*2);
  _Float16* B4    = (_Float16*)alloc(12288*2);
  float*    al    = alar_;
  float*    ar    = alar_ + N;

  const int NB = (N + 1023) / 1024;

  pack_all_kernel<<<240, 256, 0, stream>>>(W1, Wg, W2, Wf, B1, B2, B3, B4);
  hipMemsetAsync(cnt, 0, (size_t)N*4, stream);
  count_kernel<<<RNG*CPR, 256, 0, stream>>>(dst, cnt, E);
  scan1_kernel<<<NB, 1024, 0, stream>>>(cnt, incl, bsum, N);
  scan2_kernel<<<1, 64, 0, stream>>>(bsum, NB);
  scan3_kernel<<<(N+255)/256, 256, 0, stream>>>(cnt, incl, bsum, rp, fillp, dinv, N);
  fill_kernel<<<RNG*CPR, 256, 0, stream>>>(src, dst, fillp, col, E);

  const int gm  = (N + 63) / 64;
  const int g16 = (N + 15) / 16;
  const int g32 = (N + 31) / 32;

  // GEMM1: H16 = fp16( dinv ⊙ (x @ W1) )  [K=192, NT=2 -> N=128], fp32 A (read once)
  gemm_mfma_kernel<192,2,false,true,false><<<gm, 256, 0, stream>>>(
      x, B1, nullptr, dinv, nullptr, nullptr, nullptr, nullptr, H16, N, 128);
  // AGG1 (GCN): H16 -> Hb (+b1), fp16
  gcn_agg128_kernel<<<g16, 256, 0, stream>>>(H16, rp, col, dinv, b1, Hb, N);
  // GEMM2: H16 = fp16( Hb @ Wg ) (HG), fp16 A, fused al/ar (direct store)
  gemm_mfma_kernel<128,2,true,true,true><<<gm, 256, 0, stream>>>(
      Hb, B2, nullptr, nullptr, a_src, a_dst, al, ar, H16, N, 128);
  // GAT: H16 -> Hb (+bg, relu fused), fp16
  gat_agg_kernel<<<g16, 256, 0, stream>>>(H16, rp, col, al, ar, bg, Hb, N);
  // GEMM3: H16 = fp16( dinv ⊙ (Hb @ W2) )  [K=128, NT=1 -> N=64], fp16 A
  gemm_mfma_kernel<128,1,true,true,false><<<gm, 256, 0, stream>>>(
      Hb, B3, nullptr, dinv, nullptr, nullptr, nullptr, nullptr, H16, N, 64);
  // AGG2 (GCN): H16 -> Hb (+b2), fp16, F=64
  gcn_agg64_kernel<<<g32, 256, 0, stream>>>(H16, rp, col, dinv, b2, Hb, N);
  // GEMM4: out = Hb @ Wf + bf (fp32 out)  [K=64, NT=3 -> N=192], fp16 A (read once)
  gemm_mfma_kernel<64,3,true,false,false><<<gm, 256, 0, stream>>>(
      Hb, B4, bf, nullptr, nullptr, nullptr, nullptr, nullptr, d_out, N, 192);
}